// Round 5
// baseline (227.333 us; speedup 1.0000x reference)
//
#include <hip/hip_runtime.h>
#include <hip/hip_bf16.h>
#include <math.h>

// Problem constants: T=2048, B=2, E=1024, H=16, d=64
constexpr int T_DIM = 2048;
constexpr int B_DIM = 2;
constexpr int E_DIM = 1024;
// Q pre-scale folded into in_proj epilogue: d^-0.5 * log2(e); attention then
// computes p = exp2(s_scaled) = exp(s_orig * d^-0.5).
constexpr float QK_SCALE = 0.18033688011112042f;

#if __has_builtin(__builtin_amdgcn_exp2f)
#define EXP2F(x) __builtin_amdgcn_exp2f(x)
#else
#define EXP2F(x) exp2f(x)
#endif

typedef __attribute__((ext_vector_type(8))) short short8;   // 8 x bf16 (4 VGPRs)
typedef __attribute__((ext_vector_type(4))) float f32x4;    // MFMA C/D frag

__device__ inline short f2bf(float x) {
    union { __hip_bfloat16 b; short s; } u;
    u.b = __float2bfloat16(x);
    return u.s;
}
__device__ inline float bf2f(short s) {
    union { __hip_bfloat16 b; short s; } u;
    u.s = s;
    return __bfloat162float(u.b);
}

// pack two positive f32 to bf16 pair (lo in low half), RNE-ties-away.
__device__ inline int pack_bf16(float hi, float lo) {
    union { float f; unsigned u; } a, b;
    a.f = hi; b.f = lo;
    return (int)__builtin_amdgcn_perm(a.u + 0x8000u, b.u + 0x8000u, 0x07060302u);
}

__device__ inline void gl2lds16(const void* g, void* l) {
    __builtin_amdgcn_global_load_lds(
        (const __attribute__((address_space(1))) unsigned int*)g,
        (__attribute__((address_space(3))) unsigned int*)l, 16, 0, 0);
}

__device__ inline f32x4 mfma_bf16(short8 a, short8 b, f32x4 c) {
    return __builtin_amdgcn_mfma_f32_16x16x32_bf16(a, b, c, 0, 0, 0);
}

// ---------------------------------------------------------------------------
// Fused split: query (hi only), w_in (hi+lo), w_out (hi+lo). One launch.
// ---------------------------------------------------------------------------
__global__ __launch_bounds__(256)
void split_all_kernel(const float* __restrict__ query,
                      const float* __restrict__ w_in,
                      const float* __restrict__ w_out,
                      short* __restrict__ qh,
                      short* __restrict__ wih, short* __restrict__ wil,
                      short* __restrict__ woh, short* __restrict__ wol,
                      int nq4, int nwi4, int nwo4)
{
    int i = blockIdx.x * 256 + threadIdx.x;
    const float* src; short* dh; short* dl; int k; int do_lo;
    if (i < nq4) { src = query; dh = qh; dl = nullptr; k = i; do_lo = 0; }
    else if (i < nq4 + nwi4) { src = w_in; dh = wih; dl = wil; k = i - nq4; do_lo = 1; }
    else { src = w_out; dh = woh; dl = wol; k = i - nq4 - nwi4; do_lo = 1; }
    float4 v = ((const float4*)src)[k];
    short h0 = f2bf(v.x), h1 = f2bf(v.y), h2 = f2bf(v.z), h3 = f2bf(v.w);
    ((short4*)dh)[k] = make_short4(h0, h1, h2, h3);
    if (do_lo) {
        short l0 = f2bf(v.x - bf2f(h0));
        short l1 = f2bf(v.y - bf2f(h1));
        short l2 = f2bf(v.z - bf2f(h2));
        short l3 = f2bf(v.w - bf2f(h3));
        ((short4*)dl)[k] = make_short4(l0, l1, l2, l3);
    }
}

// ---------------------------------------------------------------------------
// 128x128-tile GEMM (in_proj) with FUSED repack epilogue (verified r12):
// C = A @ W^T + bias; Q cols -> qkv (pre-scaled by QK_SCALE),
// K cols -> kp in QK-MFMA frag order, V cols -> vtp in PV-MFMA frag order.
// ---------------------------------------------------------------------------
__global__ __launch_bounds__(256)
void gemm_in(const short* __restrict__ Ah,
             const short* __restrict__ Wh, const short* __restrict__ Wl,
             const float* __restrict__ bias,
             short* __restrict__ qkv, short* __restrict__ kp,
             short* __restrict__ vtp,
             int M, int N, int K)
{
    __shared__ __align__(16) short AsH[128 * 32];
    __shared__ __align__(16) short WsH[128 * 32];
    __shared__ __align__(16) short WsL[128 * 32];

    const int tid  = threadIdx.x;
    const int lane = tid & 63;
    const int wave = tid >> 6;
    const int rm = (wave >> 1) * 64;
    const int cn = (wave & 1) * 64;
    const int m0 = blockIdx.y * 128;
    const int n0 = blockIdx.x * 128;

    const int srow0 = wave * 32 + (lane >> 2);
    const int srow1 = srow0 + 16;
    const int p4 = lane & 3;
    const int kc0 = p4 ^ ((srow0 >> 1) & 3);
    const int kc1 = p4 ^ ((srow1 >> 1) & 3);

    short* ldsA0 = &AsH[(wave * 32) * 32];
    short* ldsA1 = &AsH[(wave * 32 + 16) * 32];
    short* ldsW0 = &WsH[(wave * 32) * 32];
    short* ldsW1 = &WsH[(wave * 32 + 16) * 32];
    short* ldsWl0 = &WsL[(wave * 32) * 32];
    short* ldsWl1 = &WsL[(wave * 32 + 16) * 32];

    const size_t ga0 = (size_t)(m0 + srow0) * K + kc0 * 8;
    const size_t ga1 = (size_t)(m0 + srow1) * K + kc1 * 8;
    const size_t gw0 = (size_t)(n0 + srow0) * K + kc0 * 8;
    const size_t gw1 = (size_t)(n0 + srow1) * K + kc1 * 8;

    const f32x4 zero = {0.f, 0.f, 0.f, 0.f};
    f32x4 acc[4][4];
    #pragma unroll
    for (int i = 0; i < 4; ++i)
        #pragma unroll
        for (int j = 0; j < 4; ++j) acc[i][j] = zero;

    const int fr = lane & 15;
    const int qc = lane >> 4;

    for (int k0 = 0; k0 < K; k0 += 32) {
        if (k0) __syncthreads();
        gl2lds16(Ah + ga0 + k0, ldsA0);
        gl2lds16(Ah + ga1 + k0, ldsA1);
        gl2lds16(Wh + gw0 + k0, ldsW0);
        gl2lds16(Wh + gw1 + k0, ldsW1);
        gl2lds16(Wl + gw0 + k0, ldsWl0);
        gl2lds16(Wl + gw1 + k0, ldsWl1);
        __syncthreads();

        short8 ahf[4], bhf[4], blf[4];
        #pragma unroll
        for (int i = 0; i < 4; ++i) {
            int r = rm + 16 * i + fr;
            int slot = qc ^ ((r >> 1) & 3);
            ahf[i] = *(const short8*)&AsH[r * 32 + slot * 8];
        }
        #pragma unroll
        for (int j = 0; j < 4; ++j) {
            int r = cn + 16 * j + fr;
            int slot = qc ^ ((r >> 1) & 3);
            bhf[j] = *(const short8*)&WsH[r * 32 + slot * 8];
            blf[j] = *(const short8*)&WsL[r * 32 + slot * 8];
        }
        #pragma unroll
        for (int i = 0; i < 4; ++i)
            #pragma unroll
            for (int j = 0; j < 4; ++j) {
                acc[i][j] = mfma_bf16(ahf[i], bhf[j], acc[i][j]);
                acc[i][j] = mfma_bf16(ahf[i], blf[j], acc[i][j]);
            }
    }

    const int g = lane >> 4;
    #pragma unroll
    for (int j = 0; j < 4; ++j) {
        const int colu = n0 + cn + 16 * j;     // 64-block aligned + 16j
        const int col  = colu + fr;
        const float bj = bias[col];
        const int c6  = colu >> 6;             // 3h+grp (wave-uniform)
        const int grp = c6 % 3;
        const int h   = c6 / 3;
        const int d   = (colu & 63) + fr;      // within-head coordinate
        if (grp == 0) {
            // Q -> qkv, pre-scaled
            #pragma unroll
            for (int i = 0; i < 4; ++i)
                #pragma unroll
                for (int r = 0; r < 4; ++r) {
                    int row = m0 + rm + 16 * i + g * 4 + r;
                    qkv[(size_t)row * 3072 + col] =
                        f2bf((acc[i][j][r] + bj) * QK_SCALE);
                }
        } else if (grp == 1) {
            // K -> kp in QK frag order
            const int hh = d >> 5, gk = (d >> 3) & 3, ii = d & 7;
            #pragma unroll
            for (int i = 0; i < 4; ++i)
                #pragma unroll
                for (int r = 0; r < 4; ++r) {
                    int row = m0 + rm + 16 * i + g * 4 + r;
                    int t = row >> 1, bb = row & 1;
                    int m = t & 63;
                    int R = (m & 32) | ((m & 24) >> 1) | ((m & 4) << 2) | (m & 3);
                    size_t off = (size_t)(bb * 16 + h) * 131072
                               + (size_t)(t >> 6) * 4096
                               + (size_t)(((2 * (R >> 4) + hh) * 64
                                           + gk * 16 + (R & 15)) * 8 + ii);
                    kp[off] = f2bf(acc[i][j][r] + bj);
                }
        } else {
            // V -> vtp in PV frag order
            const int jd = d >> 4, frv = d & 15;
            #pragma unroll
            for (int i = 0; i < 4; ++i)
                #pragma unroll
                for (int r = 0; r < 4; ++r) {
                    int row = m0 + rm + 16 * i + g * 4 + r;
                    int t = row >> 1, bb = row & 1;
                    int tl = t & 63;
                    size_t off = (size_t)(bb * 16 + h) * 131072
                               + (size_t)(t >> 6) * 4096
                               + (size_t)(((2 * jd + (tl >> 5)) * 64
                                           + ((tl >> 3) & 3) * 16 + frv) * 8
                                          + (tl & 7));
                    vtp[off] = f2bf(acc[i][j][r] + bj);
                }
        }
    }
}

// ---------------------------------------------------------------------------
// out_proj r13: 2-way K-split 128x128-tile GEMM, 3-MFMA full split, fp32
// partials (no bias). Old 64x128 structure was ~460-500 TF effective (half
// of gemm_in's 909): small M-tile halves MFMA per block against the same
// staging/barrier cost. 128^2 alone would give 256 blocks = 1/CU (drain
// exposed); K-split z=2 restores 512 blocks = 2/CU at full 128^2 density.
// Same-(x,y) K-halves land on the same XCD (id, id+256 = same id%8).
// Partials summed + bias in reduce_out (f32 order change only, ~1 ulp).
// ---------------------------------------------------------------------------
__global__ __launch_bounds__(256)
void gemm_out_ks(const short* __restrict__ Ah, const short* __restrict__ Al,
                 const short* __restrict__ Wh, const short* __restrict__ Wl,
                 float* __restrict__ part0, float* __restrict__ part1,
                 int M, int N, int K)
{
    __shared__ __align__(16) short AsH[128 * 32];
    __shared__ __align__(16) short AsL[128 * 32];
    __shared__ __align__(16) short WsH[128 * 32];
    __shared__ __align__(16) short WsL[128 * 32];

    const int tid  = threadIdx.x;
    const int lane = tid & 63;
    const int wave = tid >> 6;
    const int rm = (wave >> 1) * 64;
    const int cn = (wave & 1) * 64;
    const int m0 = blockIdx.y * 128;
    const int n0 = blockIdx.x * 128;
    const int kbeg = blockIdx.z * 512;
    float* __restrict__ part = blockIdx.z ? part1 : part0;

    const int srow0 = wave * 32 + (lane >> 2);
    const int srow1 = srow0 + 16;
    const int p4 = lane & 3;
    const int kc0 = p4 ^ ((srow0 >> 1) & 3);
    const int kc1 = p4 ^ ((srow1 >> 1) & 3);

    short* ldsAh0 = &AsH[(wave * 32) * 32];
    short* ldsAh1 = &AsH[(wave * 32 + 16) * 32];
    short* ldsAl0 = &AsL[(wave * 32) * 32];
    short* ldsAl1 = &AsL[(wave * 32 + 16) * 32];
    short* ldsWh0 = &WsH[(wave * 32) * 32];
    short* ldsWh1 = &WsH[(wave * 32 + 16) * 32];
    short* ldsWl0 = &WsL[(wave * 32) * 32];
    short* ldsWl1 = &WsL[(wave * 32 + 16) * 32];

    const size_t ga0 = (size_t)(m0 + srow0) * K + kbeg + kc0 * 8;
    const size_t ga1 = (size_t)(m0 + srow1) * K + kbeg + kc1 * 8;
    const size_t gw0 = (size_t)(n0 + srow0) * K + kbeg + kc0 * 8;
    const size_t gw1 = (size_t)(n0 + srow1) * K + kbeg + kc1 * 8;

    const f32x4 zero = {0.f, 0.f, 0.f, 0.f};
    f32x4 acc[4][4];
    #pragma unroll
    for (int i = 0; i < 4; ++i)
        #pragma unroll
        for (int j = 0; j < 4; ++j) acc[i][j] = zero;

    const int fr = lane & 15;
    const int qc = lane >> 4;

    for (int k0 = 0; k0 < 512; k0 += 32) {
        if (k0) __syncthreads();
        gl2lds16(Ah + ga0 + k0, ldsAh0);
        gl2lds16(Ah + ga1 + k0, ldsAh1);
        gl2lds16(Al + ga0 + k0, ldsAl0);
        gl2lds16(Al + ga1 + k0, ldsAl1);
        gl2lds16(Wh + gw0 + k0, ldsWh0);
        gl2lds16(Wh + gw1 + k0, ldsWh1);
        gl2lds16(Wl + gw0 + k0, ldsWl0);
        gl2lds16(Wl + gw1 + k0, ldsWl1);
        __syncthreads();

        short8 ahf[4], alf[4], bhf[4], blf[4];
        #pragma unroll
        for (int i = 0; i < 4; ++i) {
            int r = rm + 16 * i + fr;
            int slot = qc ^ ((r >> 1) & 3);
            ahf[i] = *(const short8*)&AsH[r * 32 + slot * 8];
            alf[i] = *(const short8*)&AsL[r * 32 + slot * 8];
        }
        #pragma unroll
        for (int j = 0; j < 4; ++j) {
            int r = cn + 16 * j + fr;
            int slot = qc ^ ((r >> 1) & 3);
            bhf[j] = *(const short8*)&WsH[r * 32 + slot * 8];
            blf[j] = *(const short8*)&WsL[r * 32 + slot * 8];
        }
        #pragma unroll
        for (int i = 0; i < 4; ++i)
            #pragma unroll
            for (int j = 0; j < 4; ++j) {
                acc[i][j] = mfma_bf16(ahf[i], bhf[j], acc[i][j]);
                acc[i][j] = mfma_bf16(ahf[i], blf[j], acc[i][j]);
                acc[i][j] = mfma_bf16(alf[i], bhf[j], acc[i][j]);
            }
    }

    const int g = lane >> 4;
    #pragma unroll
    for (int j = 0; j < 4; ++j) {
        int col = n0 + cn + 16 * j + fr;
        #pragma unroll
        for (int i = 0; i < 4; ++i)
            #pragma unroll
            for (int r = 0; r < 4; ++r) {
                int row = m0 + rm + 16 * i + g * 4 + r;
                part[(size_t)row * N + col] = acc[i][j][r];
            }
    }
}

// ---------------------------------------------------------------------------
// out = p0 + p1 + bias (float4, grid-stride). ~50 MB, L2/L3-resident.
// ---------------------------------------------------------------------------
__global__ __launch_bounds__(256)
void reduce_out(const float* __restrict__ p0, const float* __restrict__ p1,
                const float* __restrict__ bias, float* __restrict__ out,
                int n4)
{
    for (int i = blockIdx.x * 256 + threadIdx.x; i < n4; i += gridDim.x * 256) {
        float4 a = ((const float4*)p0)[i];
        float4 b = ((const float4*)p1)[i];
        float4 c = ((const float4*)bias)[i & 255];   // 1024 cols / 4
        float4 o;
        o.x = a.x + b.x + c.x;
        o.y = a.y + b.y + c.y;
        o.z = a.z + b.z + c.z;
        o.w = a.w + b.w + c.w;
        ((float4*)out)[i] = o;
    }
}

// ---------------------------------------------------------------------------
// Flash attention v12 — LDS-shared K/V, registers freed. (verified r11/r12)
// Block = 4 waves x 32 q-rows (128 q-rows) scanning all 2048 keys; K/V tiles
// staged to a 32 KB LDS double-buffer via global_load_lds, shared by all 4
// waves, read just-in-time (consecutive-16B ds_read_b128; K and V both in
// MFMA frag order, produced directly by gemm_in's fused epilogue).
// ---------------------------------------------------------------------------
__global__ __launch_bounds__(256, 2)
void attn_mfma(const short* __restrict__ qkv, const short* __restrict__ kp,
               const short* __restrict__ vtp,
               short* __restrict__ ctxh, short* __restrict__ ctxl)
{
    __shared__ __align__(16) short ldsK[2][4096];   // 16 KB
    __shared__ __align__(16) short ldsV[2][4096];   // 16 KB

    const int tid  = threadIdx.x;
    const int lane = tid & 63;
    const int wave = tid >> 6;      // 0..3 -> q-rows [wave*32, +32)
    const int fr = lane & 15;
    const int g  = lane >> 4;

    // 512 blocks = 8 XCD-groups x 4 bh x 16 q-blocks(128 rows)
    const int id = blockIdx.x;
    const int x = id & 7, y = id >> 3;
    const int bh = x * 4 + (y & 3);
    const int q0 = (y >> 2) * 128;
    const int b = bh >> 4, h = bh & 15;

    // ---- Q fragments: 2 sets of 16 rows (pre-scaled by QK_SCALE) ----
    short8 aq[2][2];
    #pragma unroll
    for (int set = 0; set < 2; ++set) {
        const short* qrow = qkv +
            ((size_t)(q0 + wave * 32 + set * 16 + fr) * 2 + b) * 3072 + h * 192;
        aq[set][0] = *(const short8*)(qrow + g * 8);
        aq[set][1] = *(const short8*)(qrow + 32 + g * 8);
    }

    const short* kt = kp  + (size_t)bh * 131072;
    const short* vt = vtp + (size_t)bh * 131072;

    short8 ONES;
    #pragma unroll
    for (int i = 0; i < 8; ++i) ONES[i] = (short)0x3F80;  // bf16 1.0

    const f32x4 zero = {0.f, 0.f, 0.f, 0.f};
    f32x4 o[2][4];
    #pragma unroll
    for (int set = 0; set < 2; ++set)
        #pragma unroll
        for (int jd = 0; jd < 4; ++jd) o[set][jd] = zero;
    f32x4 lacc[2] = {zero, zero};

    // stage one 64-key tile (K 8KB + V 8KB) into LDS buffer `sel`
    auto stage = [&](int it, int sel) {
        const short* ks = kt + it * 4096 + wave * 1024 + lane * 8;
        const short* vs = vt + it * 4096 + wave * 1024 + lane * 8;
        gl2lds16(ks,       &ldsK[sel][wave * 1024]);
        gl2lds16(ks + 512, &ldsK[sel][wave * 1024 + 512]);
        gl2lds16(vs,       &ldsV[sel][wave * 1024]);
        gl2lds16(vs + 512, &ldsV[sel][wave * 1024 + 512]);
    };

    stage(0, 0);
    #pragma unroll 2
    for (int it = 0; it < 32; ++it) {
        const int cur = it & 1;
        __syncthreads();                 // vmcnt(0) drain: stage(it) complete;
                                         // all waves done reading buf cur^1
        if (it + 1 < 32) stage(it + 1, cur ^ 1);

        // ---- QK^T + exp2 -> bf16 P fragments ----
        int afw[2][2][4];
        #pragma unroll
        for (int s = 0; s < 4; ++s) {
            short8 k0 = *(const short8*)&ldsK[cur][(2 * s) * 512 + lane * 8];
            short8 k1 = *(const short8*)&ldsK[cur][(2 * s + 1) * 512 + lane * 8];
            #pragma unroll
            for (int set = 0; set < 2; ++set) {
                f32x4 a = zero;
                a = mfma_bf16(k0, aq[set][0], a);
                a = mfma_bf16(k1, aq[set][1], a);
                float e0 = EXP2F(a[0]), e1 = EXP2F(a[1]);
                float e2 = EXP2F(a[2]), e3 = EXP2F(a[3]);
                afw[set][s >> 1][(s & 1) * 2]     = pack_bf16(e1, e0);
                afw[set][s >> 1][(s & 1) * 2 + 1] = pack_bf16(e3, e2);
            }
        }
        union { int w[4]; short8 v; } A[2][2];
        #pragma unroll
        for (int set = 0; set < 2; ++set)
            #pragma unroll
            for (int hh = 0; hh < 2; ++hh)
                #pragma unroll
                for (int w = 0; w < 4; ++w) A[set][hh].w[w] = afw[set][hh][w];

        #pragma unroll
        for (int set = 0; set < 2; ++set) {
            lacc[set] = mfma_bf16(A[set][0].v, ONES, lacc[set]);
            lacc[set] = mfma_bf16(A[set][1].v, ONES, lacc[set]);
        }

        // ---- PV: V frags read once, used by both q-sets ----
        #pragma unroll
        for (int jd = 0; jd < 4; ++jd) {
            short8 v0 = *(const short8*)&ldsV[cur][(2 * jd) * 512 + lane * 8];
            short8 v1 = *(const short8*)&ldsV[cur][(2 * jd + 1) * 512 + lane * 8];
            #pragma unroll
            for (int set = 0; set < 2; ++set) {
                o[set][jd] = mfma_bf16(A[set][0].v, v0, o[set][jd]);
                o[set][jd] = mfma_bf16(A[set][1].v, v1, o[set][jd]);
            }
        }
    }

    // ---- epilogue: normalize (lacc C-layout matches o), split, store ----
    #pragma unroll
    for (int set = 0; set < 2; ++set)
        #pragma unroll
        for (int r = 0; r < 4; ++r) {
            float inv = 1.f / lacc[set][r];
            int t = q0 + wave * 32 + set * 16 + 4 * g + r;
            size_t base = ((size_t)t * B_DIM + b) * E_DIM + h * 64;
            #pragma unroll
            for (int jd = 0; jd < 4; ++jd) {
                float v = o[set][jd][r] * inv;
                short hs = f2bf(v);
                short ls = f2bf(v - bf2f(hs));
                ctxh[base + 16 * jd + fr] = hs;
                ctxl[base + 16 * jd + fr] = ls;
            }
        }
}

// ---------------------------------------------------------------------------
extern "C" void kernel_launch(void* const* d_in, const int* in_sizes, int n_in,
                              void* d_out, int out_size, void* d_ws, size_t ws_size,
                              hipStream_t stream)
{
    const float* query = (const float*)d_in[0];
    const float* w_in  = (const float*)d_in[1];
    const float* b_in  = (const float*)d_in[2];
    const float* w_out = (const float*)d_in[3];
    const float* b_out = (const float*)d_in[4];
    float* out = (float*)d_out;

    char* ws = (char*)d_ws;
    short* qkv  = (short*)(ws);                  // 25.2 MB (Q cols live)
    short* qh   = (short*)(ws + 25165824);       // 8.4 MB
    short* wih  = (short*)(ws + 33554432);       // 6.3 MB
    short* wil  = (short*)(ws + 39845888);       // 6.3 MB
    short* woh  = (short*)(ws + 46137344);       // 2.1 MB
    short* wol  = (short*)(ws + 48234496);       // 2.1 MB
    short* vtp  = (short*)(ws + 50331648);       // 8.4 MB  V frag-order
    short* kp   = (short*)(ws + 58720256);       // 8.4 MB  K frag-order
    short* ctxh = (short*)(ws + 25165824);       // alias qh  (dead after in_proj)
    short* ctxl = (short*)(ws + 33554432);       // alias wih (dead after in_proj)
    // fp32 out_proj partials, aliased over buffers dead after attn:
    float* p0   = (float*)(ws);                  // 16.8 MB over qkv
    float* p1   = (float*)(ws + 50331648);       // 16.8 MB over vtp+kp

    const int M = T_DIM * B_DIM;  // 4096

    int nq4  = (M * E_DIM) / 4;
    int nwi4 = (3 * E_DIM * E_DIM) / 4;
    int nwo4 = (E_DIM * E_DIM) / 4;
    split_all_kernel<<<(nq4 + nwi4 + nwo4) / 256, 256, 0, stream>>>(
        query, w_in, w_out, qh, wih, wil, woh, wol, nq4, nwi4, nwo4);

    // in_proj + fused repack: Q -> qkv (scaled), K -> kp, V -> vtp
    gemm_in<<<dim3(3 * E_DIM / 128, M / 128), 256, 0, stream>>>(
        qh, wih, wil, b_in, qkv, kp, vtp, M, 3 * E_DIM, E_DIM);

    // attention: 512 blocks x 256 threads (4 waves x 32 q-rows, LDS K/V dbuf)
    attn_mfma<<<dim3(512), 256, 0, stream>>>(qkv, kp, vtp, ctxh, ctxl);

    // out_proj: 2-way K-split 128x128 tiles -> 512 blocks, 3-MFMA split
    gemm_out_ks<<<dim3(E_DIM / 128, M / 128, 2), 256, 0, stream>>>(
        ctxh, ctxl, woh, wol, p0, p1, M, E_DIM, E_DIM);

    // final: out = p0 + p1 + bias
    reduce_out<<<2048, 256, 0, stream>>>(p0, p1, b_out, out, (M * E_DIM) / 4);
}

// Round 6
// 208.426 us; speedup vs baseline: 1.0907x; 1.0907x over previous
//
#include <hip/hip_runtime.h>
#include <hip/hip_bf16.h>
#include <math.h>

// Problem constants: T=2048, B=2, E=1024, H=16, d=64
constexpr int T_DIM = 2048;
constexpr int B_DIM = 2;
constexpr int E_DIM = 1024;
// Q pre-scale folded into in_proj epilogue: d^-0.5 * log2(e); attention then
// computes p = exp2(s_scaled) = exp(s_orig * d^-0.5).
constexpr float QK_SCALE = 0.18033688011112042f;

#if __has_builtin(__builtin_amdgcn_exp2f)
#define EXP2F(x) __builtin_amdgcn_exp2f(x)
#else
#define EXP2F(x) exp2f(x)
#endif

typedef __attribute__((ext_vector_type(8))) short short8;   // 8 x bf16 (4 VGPRs)
typedef __attribute__((ext_vector_type(4))) float f32x4;    // MFMA C/D frag

__device__ inline short f2bf(float x) {
    union { __hip_bfloat16 b; short s; } u;
    u.b = __float2bfloat16(x);
    return u.s;
}
__device__ inline float bf2f(short s) {
    union { __hip_bfloat16 b; short s; } u;
    u.s = s;
    return __bfloat162float(u.b);
}

// pack two positive f32 to bf16 pair (lo in low half), RNE-ties-away.
__device__ inline int pack_bf16(float hi, float lo) {
    union { float f; unsigned u; } a, b;
    a.f = hi; b.f = lo;
    return (int)__builtin_amdgcn_perm(a.u + 0x8000u, b.u + 0x8000u, 0x07060302u);
}

__device__ inline void gl2lds16(const void* g, void* l) {
    __builtin_amdgcn_global_load_lds(
        (const __attribute__((address_space(1))) unsigned int*)g,
        (__attribute__((address_space(3))) unsigned int*)l, 16, 0, 0);
}

__device__ inline f32x4 mfma_bf16(short8 a, short8 b, f32x4 c) {
    return __builtin_amdgcn_mfma_f32_16x16x32_bf16(a, b, c, 0, 0, 0);
}

// ---------------------------------------------------------------------------
// Fused split: query (hi only), w_in (hi+lo), w_out (hi+lo). One launch.
// ---------------------------------------------------------------------------
__global__ __launch_bounds__(256)
void split_all_kernel(const float* __restrict__ query,
                      const float* __restrict__ w_in,
                      const float* __restrict__ w_out,
                      short* __restrict__ qh,
                      short* __restrict__ wih, short* __restrict__ wil,
                      short* __restrict__ woh, short* __restrict__ wol,
                      int nq4, int nwi4, int nwo4)
{
    int i = blockIdx.x * 256 + threadIdx.x;
    const float* src; short* dh; short* dl; int k; int do_lo;
    if (i < nq4) { src = query; dh = qh; dl = nullptr; k = i; do_lo = 0; }
    else if (i < nq4 + nwi4) { src = w_in; dh = wih; dl = wil; k = i - nq4; do_lo = 1; }
    else { src = w_out; dh = woh; dl = wol; k = i - nq4 - nwi4; do_lo = 1; }
    float4 v = ((const float4*)src)[k];
    short h0 = f2bf(v.x), h1 = f2bf(v.y), h2 = f2bf(v.z), h3 = f2bf(v.w);
    ((short4*)dh)[k] = make_short4(h0, h1, h2, h3);
    if (do_lo) {
        short l0 = f2bf(v.x - bf2f(h0));
        short l1 = f2bf(v.y - bf2f(h1));
        short l2 = f2bf(v.z - bf2f(h2));
        short l3 = f2bf(v.w - bf2f(h3));
        ((short4*)dl)[k] = make_short4(l0, l1, l2, l3);
    }
}

// ---------------------------------------------------------------------------
// 128x128-tile GEMM (in_proj), BK=64 (r14): halves the per-K-step
// vmcnt(0)+barrier drain count (33 -> 17) that dominates the ~44% idle
// fraction at MfmaUtil 37%. 3-bit XOR slot swizzle: LDS[r][p] = G[r][p^(r&7)]
// staged via linear-dest gl2lds (slot = (lane&7)^(lane>>3) in the per-lane
// GLOBAL address), read at slot (4*kk+qc)^(r&7) -> 2-way bank alias = free.
// FUSED repack epilogue (verified r12): Q -> qkv (pre-scaled), K -> kp
// (QK-MFMA frag order), V -> vtp (PV-MFMA frag order).
// ---------------------------------------------------------------------------
__global__ __launch_bounds__(256)
void gemm_in(const short* __restrict__ Ah,
             const short* __restrict__ Wh, const short* __restrict__ Wl,
             const float* __restrict__ bias,
             short* __restrict__ qkv, short* __restrict__ kp,
             short* __restrict__ vtp,
             int M, int N, int K)
{
    __shared__ __align__(16) short AsH[128 * 64];
    __shared__ __align__(16) short WsH[128 * 64];
    __shared__ __align__(16) short WsL[128 * 64];

    const int tid  = threadIdx.x;
    const int lane = tid & 63;
    const int wave = tid >> 6;
    const int rm = (wave >> 1) * 64;
    const int cn = (wave & 1) * 64;
    const int m0 = blockIdx.y * 128;
    const int n0 = blockIdx.x * 128;

    // staging: each wave covers 32 rows of A/Wh/Wl in 4 chunks of 8 rows
    const int srow = wave * 32 + (lane >> 3);
    const int swz  = (lane & 7) ^ (lane >> 3);    // 16B-slot XOR swizzle
    const size_t gaB = (size_t)(m0 + srow) * K + swz * 8;
    const size_t gwB = (size_t)(n0 + srow) * K + swz * 8;
    const size_t rowK8 = (size_t)8 * K;

    const f32x4 zero = {0.f, 0.f, 0.f, 0.f};
    f32x4 acc[4][4];
    #pragma unroll
    for (int i = 0; i < 4; ++i)
        #pragma unroll
        for (int j = 0; j < 4; ++j) acc[i][j] = zero;

    const int fr = lane & 15;
    const int qc = lane >> 4;

    for (int k0 = 0; k0 < K; k0 += 64) {
        if (k0) __syncthreads();
        #pragma unroll
        for (int c = 0; c < 4; ++c) {
            gl2lds16(Ah + gaB + k0 + c * rowK8, &AsH[(wave * 32 + c * 8) * 64]);
            gl2lds16(Wh + gwB + k0 + c * rowK8, &WsH[(wave * 32 + c * 8) * 64]);
            gl2lds16(Wl + gwB + k0 + c * rowK8, &WsL[(wave * 32 + c * 8) * 64]);
        }
        __syncthreads();

        #pragma unroll
        for (int kk = 0; kk < 2; ++kk) {
            short8 ahf[4], bhf[4], blf[4];
            #pragma unroll
            for (int i = 0; i < 4; ++i) {
                int r = rm + 16 * i + fr;
                int slot = (4 * kk + qc) ^ (r & 7);
                ahf[i] = *(const short8*)&AsH[r * 64 + slot * 8];
            }
            #pragma unroll
            for (int j = 0; j < 4; ++j) {
                int r = cn + 16 * j + fr;
                int slot = (4 * kk + qc) ^ (r & 7);
                bhf[j] = *(const short8*)&WsH[r * 64 + slot * 8];
                blf[j] = *(const short8*)&WsL[r * 64 + slot * 8];
            }
            #pragma unroll
            for (int i = 0; i < 4; ++i)
                #pragma unroll
                for (int j = 0; j < 4; ++j) {
                    acc[i][j] = mfma_bf16(ahf[i], bhf[j], acc[i][j]);
                    acc[i][j] = mfma_bf16(ahf[i], blf[j], acc[i][j]);
                }
        }
    }

    const int g = lane >> 4;
    #pragma unroll
    for (int j = 0; j < 4; ++j) {
        const int colu = n0 + cn + 16 * j;     // 64-block aligned + 16j
        const int col  = colu + fr;
        const float bj = bias[col];
        const int c6  = colu >> 6;             // 3h+grp (wave-uniform)
        const int grp = c6 % 3;
        const int h   = c6 / 3;
        const int d   = (colu & 63) + fr;      // within-head coordinate
        if (grp == 0) {
            // Q -> qkv, pre-scaled
            #pragma unroll
            for (int i = 0; i < 4; ++i)
                #pragma unroll
                for (int r = 0; r < 4; ++r) {
                    int row = m0 + rm + 16 * i + g * 4 + r;
                    qkv[(size_t)row * 3072 + col] =
                        f2bf((acc[i][j][r] + bj) * QK_SCALE);
                }
        } else if (grp == 1) {
            // K -> kp in QK frag order
            const int hh = d >> 5, gk = (d >> 3) & 3, ii = d & 7;
            #pragma unroll
            for (int i = 0; i < 4; ++i)
                #pragma unroll
                for (int r = 0; r < 4; ++r) {
                    int row = m0 + rm + 16 * i + g * 4 + r;
                    int t = row >> 1, bb = row & 1;
                    int m = t & 63;
                    int R = (m & 32) | ((m & 24) >> 1) | ((m & 4) << 2) | (m & 3);
                    size_t off = (size_t)(bb * 16 + h) * 131072
                               + (size_t)(t >> 6) * 4096
                               + (size_t)(((2 * (R >> 4) + hh) * 64
                                           + gk * 16 + (R & 15)) * 8 + ii);
                    kp[off] = f2bf(acc[i][j][r] + bj);
                }
        } else {
            // V -> vtp in PV frag order
            const int jd = d >> 4, frv = d & 15;
            #pragma unroll
            for (int i = 0; i < 4; ++i)
                #pragma unroll
                for (int r = 0; r < 4; ++r) {
                    int row = m0 + rm + 16 * i + g * 4 + r;
                    int t = row >> 1, bb = row & 1;
                    int tl = t & 63;
                    size_t off = (size_t)(bb * 16 + h) * 131072
                               + (size_t)(t >> 6) * 4096
                               + (size_t)(((2 * jd + (tl >> 5)) * 64
                                           + ((tl >> 3) & 3) * 16 + frv) * 8
                                          + (tl & 7));
                    vtp[off] = f2bf(acc[i][j][r] + bj);
                }
        }
    }
}

// ---------------------------------------------------------------------------
// 64x128-tile GEMM (out_proj): 3-MFMA full split, fp32 out, BK=64 (r14).
// Structure verified r7/r8/r12; r13's K-split+reduce regressed (+11.5 us of
// fp32-partial round-trip traffic) and is reverted. BK=64 halves barriers.
// ---------------------------------------------------------------------------
__global__ __launch_bounds__(256)
void gemm_out(const short* __restrict__ Ah, const short* __restrict__ Al,
              const short* __restrict__ Wh, const short* __restrict__ Wl,
              const float* __restrict__ bias, float* __restrict__ Cout,
              int M, int N, int K)
{
    __shared__ __align__(16) short AsH[64 * 64];
    __shared__ __align__(16) short AsL[64 * 64];
    __shared__ __align__(16) short WsH[128 * 64];
    __shared__ __align__(16) short WsL[128 * 64];

    const int tid  = threadIdx.x;
    const int lane = tid & 63;
    const int wave = tid >> 6;
    const int m0 = blockIdx.y * 64;
    const int n0 = blockIdx.x * 128;

    // staging: A rows wave*16..+16 (2 chunks), W rows wave*32..+32 (4 chunks)
    const int sarow = wave * 16 + (lane >> 3);
    const int swrow = wave * 32 + (lane >> 3);
    const int swz   = (lane & 7) ^ (lane >> 3);
    const size_t gaB = (size_t)(m0 + sarow) * K + swz * 8;
    const size_t gwB = (size_t)(n0 + swrow) * K + swz * 8;
    const size_t rowK8 = (size_t)8 * K;

    const f32x4 zero = {0.f, 0.f, 0.f, 0.f};
    f32x4 acc[4][2];
    #pragma unroll
    for (int i = 0; i < 4; ++i) { acc[i][0] = zero; acc[i][1] = zero; }

    const int fr = lane & 15;
    const int g = lane >> 4;

    for (int k0 = 0; k0 < K; k0 += 64) {
        if (k0) __syncthreads();
        #pragma unroll
        for (int c = 0; c < 2; ++c) {
            gl2lds16(Ah + gaB + k0 + c * rowK8, &AsH[(wave * 16 + c * 8) * 64]);
            gl2lds16(Al + gaB + k0 + c * rowK8, &AsL[(wave * 16 + c * 8) * 64]);
        }
        #pragma unroll
        for (int c = 0; c < 4; ++c) {
            gl2lds16(Wh + gwB + k0 + c * rowK8, &WsH[(wave * 32 + c * 8) * 64]);
            gl2lds16(Wl + gwB + k0 + c * rowK8, &WsL[(wave * 32 + c * 8) * 64]);
        }
        __syncthreads();

        #pragma unroll
        for (int kk = 0; kk < 2; ++kk) {
            short8 ahf[4], alf[4], bhf[2], blf[2];
            #pragma unroll
            for (int i = 0; i < 4; ++i) {
                int r = 16 * i + fr;
                int slot = (4 * kk + g) ^ (r & 7);
                ahf[i] = *(const short8*)&AsH[r * 64 + slot * 8];
                alf[i] = *(const short8*)&AsL[r * 64 + slot * 8];
            }
            #pragma unroll
            for (int j = 0; j < 2; ++j) {
                int r = wave * 32 + 16 * j + fr;
                int slot = (4 * kk + g) ^ (r & 7);
                bhf[j] = *(const short8*)&WsH[r * 64 + slot * 8];
                blf[j] = *(const short8*)&WsL[r * 64 + slot * 8];
            }
            #pragma unroll
            for (int i = 0; i < 4; ++i)
                #pragma unroll
                for (int j = 0; j < 2; ++j) {
                    acc[i][j] = mfma_bf16(ahf[i], bhf[j], acc[i][j]);
                    acc[i][j] = mfma_bf16(ahf[i], blf[j], acc[i][j]);
                    acc[i][j] = mfma_bf16(alf[i], bhf[j], acc[i][j]);
                }
        }
    }

    #pragma unroll
    for (int j = 0; j < 2; ++j) {
        int col = n0 + wave * 32 + 16 * j + fr;
        float bj = bias[col];
        #pragma unroll
        for (int i = 0; i < 4; ++i)
            #pragma unroll
            for (int r = 0; r < 4; ++r) {
                int row = m0 + 16 * i + g * 4 + r;
                Cout[(size_t)row * N + col] = acc[i][j][r] + bj;
            }
    }
}

// ---------------------------------------------------------------------------
// Flash attention v12 — LDS-shared K/V, registers freed. (verified r11/r12)
// Block = 4 waves x 32 q-rows (128 q-rows) scanning all 2048 keys; K/V tiles
// staged to a 32 KB LDS double-buffer via global_load_lds, shared by all 4
// waves, read just-in-time (consecutive-16B ds_read_b128; K and V both in
// MFMA frag order, produced directly by gemm_in's fused epilogue).
// ---------------------------------------------------------------------------
__global__ __launch_bounds__(256, 2)
void attn_mfma(const short* __restrict__ qkv, const short* __restrict__ kp,
               const short* __restrict__ vtp,
               short* __restrict__ ctxh, short* __restrict__ ctxl)
{
    __shared__ __align__(16) short ldsK[2][4096];   // 16 KB
    __shared__ __align__(16) short ldsV[2][4096];   // 16 KB

    const int tid  = threadIdx.x;
    const int lane = tid & 63;
    const int wave = tid >> 6;      // 0..3 -> q-rows [wave*32, +32)
    const int fr = lane & 15;
    const int g  = lane >> 4;

    // 512 blocks = 8 XCD-groups x 4 bh x 16 q-blocks(128 rows)
    const int id = blockIdx.x;
    const int x = id & 7, y = id >> 3;
    const int bh = x * 4 + (y & 3);
    const int q0 = (y >> 2) * 128;
    const int b = bh >> 4, h = bh & 15;

    // ---- Q fragments: 2 sets of 16 rows (pre-scaled by QK_SCALE) ----
    short8 aq[2][2];
    #pragma unroll
    for (int set = 0; set < 2; ++set) {
        const short* qrow = qkv +
            ((size_t)(q0 + wave * 32 + set * 16 + fr) * 2 + b) * 3072 + h * 192;
        aq[set][0] = *(const short8*)(qrow + g * 8);
        aq[set][1] = *(const short8*)(qrow + 32 + g * 8);
    }

    const short* kt = kp  + (size_t)bh * 131072;
    const short* vt = vtp + (size_t)bh * 131072;

    short8 ONES;
    #pragma unroll
    for (int i = 0; i < 8; ++i) ONES[i] = (short)0x3F80;  // bf16 1.0

    const f32x4 zero = {0.f, 0.f, 0.f, 0.f};
    f32x4 o[2][4];
    #pragma unroll
    for (int set = 0; set < 2; ++set)
        #pragma unroll
        for (int jd = 0; jd < 4; ++jd) o[set][jd] = zero;
    f32x4 lacc[2] = {zero, zero};

    // stage one 64-key tile (K 8KB + V 8KB) into LDS buffer `sel`
    auto stage = [&](int it, int sel) {
        const short* ks = kt + it * 4096 + wave * 1024 + lane * 8;
        const short* vs = vt + it * 4096 + wave * 1024 + lane * 8;
        gl2lds16(ks,       &ldsK[sel][wave * 1024]);
        gl2lds16(ks + 512, &ldsK[sel][wave * 1024 + 512]);
        gl2lds16(vs,       &ldsV[sel][wave * 1024]);
        gl2lds16(vs + 512, &ldsV[sel][wave * 1024 + 512]);
    };

    stage(0, 0);
    #pragma unroll 2
    for (int it = 0; it < 32; ++it) {
        const int cur = it & 1;
        __syncthreads();                 // vmcnt(0) drain: stage(it) complete;
                                         // all waves done reading buf cur^1
        if (it + 1 < 32) stage(it + 1, cur ^ 1);

        // ---- QK^T + exp2 -> bf16 P fragments ----
        int afw[2][2][4];
        #pragma unroll
        for (int s = 0; s < 4; ++s) {
            short8 k0 = *(const short8*)&ldsK[cur][(2 * s) * 512 + lane * 8];
            short8 k1 = *(const short8*)&ldsK[cur][(2 * s + 1) * 512 + lane * 8];
            #pragma unroll
            for (int set = 0; set < 2; ++set) {
                f32x4 a = zero;
                a = mfma_bf16(k0, aq[set][0], a);
                a = mfma_bf16(k1, aq[set][1], a);
                float e0 = EXP2F(a[0]), e1 = EXP2F(a[1]);
                float e2 = EXP2F(a[2]), e3 = EXP2F(a[3]);
                afw[set][s >> 1][(s & 1) * 2]     = pack_bf16(e1, e0);
                afw[set][s >> 1][(s & 1) * 2 + 1] = pack_bf16(e3, e2);
            }
        }
        union { int w[4]; short8 v; } A[2][2];
        #pragma unroll
        for (int set = 0; set < 2; ++set)
            #pragma unroll
            for (int hh = 0; hh < 2; ++hh)
                #pragma unroll
                for (int w = 0; w < 4; ++w) A[set][hh].w[w] = afw[set][hh][w];

        #pragma unroll
        for (int set = 0; set < 2; ++set) {
            lacc[set] = mfma_bf16(A[set][0].v, ONES, lacc[set]);
            lacc[set] = mfma_bf16(A[set][1].v, ONES, lacc[set]);
        }

        // ---- PV: V frags read once, used by both q-sets ----
        #pragma unroll
        for (int jd = 0; jd < 4; ++jd) {
            short8 v0 = *(const short8*)&ldsV[cur][(2 * jd) * 512 + lane * 8];
            short8 v1 = *(const short8*)&ldsV[cur][(2 * jd + 1) * 512 + lane * 8];
            #pragma unroll
            for (int set = 0; set < 2; ++set) {
                o[set][jd] = mfma_bf16(A[set][0].v, v0, o[set][jd]);
                o[set][jd] = mfma_bf16(A[set][1].v, v1, o[set][jd]);
            }
        }
    }

    // ---- epilogue: normalize (lacc C-layout matches o), split, store ----
    #pragma unroll
    for (int set = 0; set < 2; ++set)
        #pragma unroll
        for (int r = 0; r < 4; ++r) {
            float inv = 1.f / lacc[set][r];
            int t = q0 + wave * 32 + set * 16 + 4 * g + r;
            size_t base = ((size_t)t * B_DIM + b) * E_DIM + h * 64;
            #pragma unroll
            for (int jd = 0; jd < 4; ++jd) {
                float v = o[set][jd][r] * inv;
                short hs = f2bf(v);
                short ls = f2bf(v - bf2f(hs));
                ctxh[base + 16 * jd + fr] = hs;
                ctxl[base + 16 * jd + fr] = ls;
            }
        }
}

// ---------------------------------------------------------------------------
extern "C" void kernel_launch(void* const* d_in, const int* in_sizes, int n_in,
                              void* d_out, int out_size, void* d_ws, size_t ws_size,
                              hipStream_t stream)
{
    const float* query = (const float*)d_in[0];
    const float* w_in  = (const float*)d_in[1];
    const float* b_in  = (const float*)d_in[2];
    const float* w_out = (const float*)d_in[3];
    const float* b_out = (const float*)d_in[4];
    float* out = (float*)d_out;

    char* ws = (char*)d_ws;
    short* qkv  = (short*)(ws);                  // 25.2 MB (Q cols live)
    short* qh   = (short*)(ws + 25165824);       // 8.4 MB
    short* wih  = (short*)(ws + 33554432);       // 6.3 MB
    short* wil  = (short*)(ws + 39845888);       // 6.3 MB
    short* woh  = (short*)(ws + 46137344);       // 2.1 MB
    short* wol  = (short*)(ws + 48234496);       // 2.1 MB
    short* vtp  = (short*)(ws + 50331648);       // 8.4 MB  V frag-order
    short* kp   = (short*)(ws + 58720256);       // 8.4 MB  K frag-order
    short* ctxh = (short*)(ws + 25165824);       // alias qh  (dead after in_proj)
    short* ctxl = (short*)(ws + 33554432);       // alias wih (dead after in_proj)

    const int M = T_DIM * B_DIM;  // 4096

    int nq4  = (M * E_DIM) / 4;
    int nwi4 = (3 * E_DIM * E_DIM) / 4;
    int nwo4 = (E_DIM * E_DIM) / 4;
    split_all_kernel<<<(nq4 + nwi4 + nwo4) / 256, 256, 0, stream>>>(
        query, w_in, w_out, qh, wih, wil, woh, wol, nq4, nwi4, nwo4);

    // in_proj + fused repack: Q -> qkv (scaled), K -> kp, V -> vtp
    gemm_in<<<dim3(3 * E_DIM / 128, M / 128), 256, 0, stream>>>(
        qh, wih, wil, b_in, qkv, kp, vtp, M, 3 * E_DIM, E_DIM);

    // attention: 512 blocks x 256 threads (4 waves x 32 q-rows, LDS K/V dbuf)
    attn_mfma<<<dim3(512), 256, 0, stream>>>(qkv, kp, vtp, ctxh, ctxl);

    // out_proj: 64x128 tiles -> 512 blocks, full split, 3 MFMA, BK=64
    gemm_out<<<dim3(E_DIM / 128, M / 64), 256, 0, stream>>>(
        ctxh, ctxl, woh, wol, b_out, out, M, E_DIM, E_DIM);
}

// Round 7
// 194.708 us; speedup vs baseline: 1.1676x; 1.0705x over previous
//
#include <hip/hip_runtime.h>
#include <hip/hip_bf16.h>
#include <math.h>

// Problem constants: T=2048, B=2, E=1024, H=16, d=64
constexpr int T_DIM = 2048;
constexpr int B_DIM = 2;
constexpr int E_DIM = 1024;
// Q pre-scale folded into in_proj epilogue: d^-0.5 * log2(e); attention then
// computes p = exp2(s_scaled) = exp(s_orig * d^-0.5).
constexpr float QK_SCALE = 0.18033688011112042f;

#if __has_builtin(__builtin_amdgcn_exp2f)
#define EXP2F(x) __builtin_amdgcn_exp2f(x)
#else
#define EXP2F(x) exp2f(x)
#endif

typedef __attribute__((ext_vector_type(8))) short short8;   // 8 x bf16 (4 VGPRs)
typedef __attribute__((ext_vector_type(4))) float f32x4;    // MFMA C/D frag

__device__ inline short f2bf(float x) {
    union { __hip_bfloat16 b; short s; } u;
    u.b = __float2bfloat16(x);
    return u.s;
}
__device__ inline float bf2f(short s) {
    union { __hip_bfloat16 b; short s; } u;
    u.s = s;
    return __bfloat162float(u.b);
}

// pack two positive f32 to bf16 pair (lo in low half), RNE-ties-away.
__device__ inline int pack_bf16(float hi, float lo) {
    union { float f; unsigned u; } a, b;
    a.f = hi; b.f = lo;
    return (int)__builtin_amdgcn_perm(a.u + 0x8000u, b.u + 0x8000u, 0x07060302u);
}

__device__ inline void gl2lds16(const void* g, void* l) {
    __builtin_amdgcn_global_load_lds(
        (const __attribute__((address_space(1))) unsigned int*)g,
        (__attribute__((address_space(3))) unsigned int*)l, 16, 0, 0);
}

__device__ inline f32x4 mfma_bf16(short8 a, short8 b, f32x4 c) {
    return __builtin_amdgcn_mfma_f32_16x16x32_bf16(a, b, c, 0, 0, 0);
}

// ---------------------------------------------------------------------------
// Fused split: query (hi only), w_in (hi+lo), w_out (hi+lo). One launch.
// ---------------------------------------------------------------------------
__global__ __launch_bounds__(256)
void split_all_kernel(const float* __restrict__ query,
                      const float* __restrict__ w_in,
                      const float* __restrict__ w_out,
                      short* __restrict__ qh,
                      short* __restrict__ wih, short* __restrict__ wil,
                      short* __restrict__ woh, short* __restrict__ wol,
                      int nq4, int nwi4, int nwo4)
{
    int i = blockIdx.x * 256 + threadIdx.x;
    const float* src; short* dh; short* dl; int k; int do_lo;
    if (i < nq4) { src = query; dh = qh; dl = nullptr; k = i; do_lo = 0; }
    else if (i < nq4 + nwi4) { src = w_in; dh = wih; dl = wil; k = i - nq4; do_lo = 1; }
    else { src = w_out; dh = woh; dl = wol; k = i - nq4 - nwi4; do_lo = 1; }
    float4 v = ((const float4*)src)[k];
    short h0 = f2bf(v.x), h1 = f2bf(v.y), h2 = f2bf(v.z), h3 = f2bf(v.w);
    ((short4*)dh)[k] = make_short4(h0, h1, h2, h3);
    if (do_lo) {
        short l0 = f2bf(v.x - bf2f(h0));
        short l1 = f2bf(v.y - bf2f(h1));
        short l2 = f2bf(v.z - bf2f(h2));
        short l3 = f2bf(v.w - bf2f(h3));
        ((short4*)dl)[k] = make_short4(l0, l1, l2, l3);
    }
}

// ---------------------------------------------------------------------------
// 128x128-tile GEMM (in_proj), BK=64 (verified r14: 57.4 -> 48.6 us,
// MfmaUtil 45%). 3-bit XOR slot swizzle; FUSED repack epilogue (r12):
// Q -> qkv (pre-scaled), K -> kp (QK frag order), V -> vtp (PV frag order).
// ---------------------------------------------------------------------------
__global__ __launch_bounds__(256)
void gemm_in(const short* __restrict__ Ah,
             const short* __restrict__ Wh, const short* __restrict__ Wl,
             const float* __restrict__ bias,
             short* __restrict__ qkv, short* __restrict__ kp,
             short* __restrict__ vtp,
             int M, int N, int K)
{
    __shared__ __align__(16) short AsH[128 * 64];
    __shared__ __align__(16) short WsH[128 * 64];
    __shared__ __align__(16) short WsL[128 * 64];

    const int tid  = threadIdx.x;
    const int lane = tid & 63;
    const int wave = tid >> 6;
    const int rm = (wave >> 1) * 64;
    const int cn = (wave & 1) * 64;
    const int m0 = blockIdx.y * 128;
    const int n0 = blockIdx.x * 128;

    // staging: each wave covers 32 rows of A/Wh/Wl in 4 chunks of 8 rows
    const int srow = wave * 32 + (lane >> 3);
    const int swz  = (lane & 7) ^ (lane >> 3);    // 16B-slot XOR swizzle
    const size_t gaB = (size_t)(m0 + srow) * K + swz * 8;
    const size_t gwB = (size_t)(n0 + srow) * K + swz * 8;
    const size_t rowK8 = (size_t)8 * K;

    const f32x4 zero = {0.f, 0.f, 0.f, 0.f};
    f32x4 acc[4][4];
    #pragma unroll
    for (int i = 0; i < 4; ++i)
        #pragma unroll
        for (int j = 0; j < 4; ++j) acc[i][j] = zero;

    const int fr = lane & 15;
    const int qc = lane >> 4;

    for (int k0 = 0; k0 < K; k0 += 64) {
        if (k0) __syncthreads();
        #pragma unroll
        for (int c = 0; c < 4; ++c) {
            gl2lds16(Ah + gaB + k0 + c * rowK8, &AsH[(wave * 32 + c * 8) * 64]);
            gl2lds16(Wh + gwB + k0 + c * rowK8, &WsH[(wave * 32 + c * 8) * 64]);
            gl2lds16(Wl + gwB + k0 + c * rowK8, &WsL[(wave * 32 + c * 8) * 64]);
        }
        __syncthreads();

        #pragma unroll
        for (int kk = 0; kk < 2; ++kk) {
            short8 ahf[4], bhf[4], blf[4];
            #pragma unroll
            for (int i = 0; i < 4; ++i) {
                int r = rm + 16 * i + fr;
                int slot = (4 * kk + qc) ^ (r & 7);
                ahf[i] = *(const short8*)&AsH[r * 64 + slot * 8];
            }
            #pragma unroll
            for (int j = 0; j < 4; ++j) {
                int r = cn + 16 * j + fr;
                int slot = (4 * kk + qc) ^ (r & 7);
                bhf[j] = *(const short8*)&WsH[r * 64 + slot * 8];
                blf[j] = *(const short8*)&WsL[r * 64 + slot * 8];
            }
            #pragma unroll
            for (int i = 0; i < 4; ++i)
                #pragma unroll
                for (int j = 0; j < 4; ++j) {
                    acc[i][j] = mfma_bf16(ahf[i], bhf[j], acc[i][j]);
                    acc[i][j] = mfma_bf16(ahf[i], blf[j], acc[i][j]);
                }
        }
    }

    const int g = lane >> 4;
    #pragma unroll
    for (int j = 0; j < 4; ++j) {
        const int colu = n0 + cn + 16 * j;     // 64-block aligned + 16j
        const int col  = colu + fr;
        const float bj = bias[col];
        const int c6  = colu >> 6;             // 3h+grp (wave-uniform)
        const int grp = c6 % 3;
        const int h   = c6 / 3;
        const int d   = (colu & 63) + fr;      // within-head coordinate
        if (grp == 0) {
            // Q -> qkv, pre-scaled
            #pragma unroll
            for (int i = 0; i < 4; ++i)
                #pragma unroll
                for (int r = 0; r < 4; ++r) {
                    int row = m0 + rm + 16 * i + g * 4 + r;
                    qkv[(size_t)row * 3072 + col] =
                        f2bf((acc[i][j][r] + bj) * QK_SCALE);
                }
        } else if (grp == 1) {
            // K -> kp in QK frag order
            const int hh = d >> 5, gk = (d >> 3) & 3, ii = d & 7;
            #pragma unroll
            for (int i = 0; i < 4; ++i)
                #pragma unroll
                for (int r = 0; r < 4; ++r) {
                    int row = m0 + rm + 16 * i + g * 4 + r;
                    int t = row >> 1, bb = row & 1;
                    int m = t & 63;
                    int R = (m & 32) | ((m & 24) >> 1) | ((m & 4) << 2) | (m & 3);
                    size_t off = (size_t)(bb * 16 + h) * 131072
                               + (size_t)(t >> 6) * 4096
                               + (size_t)(((2 * (R >> 4) + hh) * 64
                                           + gk * 16 + (R & 15)) * 8 + ii);
                    kp[off] = f2bf(acc[i][j][r] + bj);
                }
        } else {
            // V -> vtp in PV frag order
            const int jd = d >> 4, frv = d & 15;
            #pragma unroll
            for (int i = 0; i < 4; ++i)
                #pragma unroll
                for (int r = 0; r < 4; ++r) {
                    int row = m0 + rm + 16 * i + g * 4 + r;
                    int t = row >> 1, bb = row & 1;
                    int tl = t & 63;
                    size_t off = (size_t)(bb * 16 + h) * 131072
                               + (size_t)(t >> 6) * 4096
                               + (size_t)(((2 * jd + (tl >> 5)) * 64
                                           + ((tl >> 3) & 3) * 16 + frv) * 8
                                          + (tl & 7));
                    vtp[off] = f2bf(acc[i][j][r] + bj);
                }
        }
    }
}

// ---------------------------------------------------------------------------
// 64x128-tile GEMM (out_proj): 3-MFMA full split, fp32 out, BK=64 (r14).
// ---------------------------------------------------------------------------
__global__ __launch_bounds__(256)
void gemm_out(const short* __restrict__ Ah, const short* __restrict__ Al,
              const short* __restrict__ Wh, const short* __restrict__ Wl,
              const float* __restrict__ bias, float* __restrict__ Cout,
              int M, int N, int K)
{
    __shared__ __align__(16) short AsH[64 * 64];
    __shared__ __align__(16) short AsL[64 * 64];
    __shared__ __align__(16) short WsH[128 * 64];
    __shared__ __align__(16) short WsL[128 * 64];

    const int tid  = threadIdx.x;
    const int lane = tid & 63;
    const int wave = tid >> 6;
    const int m0 = blockIdx.y * 64;
    const int n0 = blockIdx.x * 128;

    // staging: A rows wave*16..+16 (2 chunks), W rows wave*32..+32 (4 chunks)
    const int sarow = wave * 16 + (lane >> 3);
    const int swrow = wave * 32 + (lane >> 3);
    const int swz   = (lane & 7) ^ (lane >> 3);
    const size_t gaB = (size_t)(m0 + sarow) * K + swz * 8;
    const size_t gwB = (size_t)(n0 + swrow) * K + swz * 8;
    const size_t rowK8 = (size_t)8 * K;

    const f32x4 zero = {0.f, 0.f, 0.f, 0.f};
    f32x4 acc[4][2];
    #pragma unroll
    for (int i = 0; i < 4; ++i) { acc[i][0] = zero; acc[i][1] = zero; }

    const int fr = lane & 15;
    const int g = lane >> 4;

    for (int k0 = 0; k0 < K; k0 += 64) {
        if (k0) __syncthreads();
        #pragma unroll
        for (int c = 0; c < 2; ++c) {
            gl2lds16(Ah + gaB + k0 + c * rowK8, &AsH[(wave * 16 + c * 8) * 64]);
            gl2lds16(Al + gaB + k0 + c * rowK8, &AsL[(wave * 16 + c * 8) * 64]);
        }
        #pragma unroll
        for (int c = 0; c < 4; ++c) {
            gl2lds16(Wh + gwB + k0 + c * rowK8, &WsH[(wave * 32 + c * 8) * 64]);
            gl2lds16(Wl + gwB + k0 + c * rowK8, &WsL[(wave * 32 + c * 8) * 64]);
        }
        __syncthreads();

        #pragma unroll
        for (int kk = 0; kk < 2; ++kk) {
            short8 ahf[4], alf[4], bhf[2], blf[2];
            #pragma unroll
            for (int i = 0; i < 4; ++i) {
                int r = 16 * i + fr;
                int slot = (4 * kk + g) ^ (r & 7);
                ahf[i] = *(const short8*)&AsH[r * 64 + slot * 8];
                alf[i] = *(const short8*)&AsL[r * 64 + slot * 8];
            }
            #pragma unroll
            for (int j = 0; j < 2; ++j) {
                int r = wave * 32 + 16 * j + fr;
                int slot = (4 * kk + g) ^ (r & 7);
                bhf[j] = *(const short8*)&WsH[r * 64 + slot * 8];
                blf[j] = *(const short8*)&WsL[r * 64 + slot * 8];
            }
            #pragma unroll
            for (int i = 0; i < 4; ++i)
                #pragma unroll
                for (int j = 0; j < 2; ++j) {
                    acc[i][j] = mfma_bf16(ahf[i], bhf[j], acc[i][j]);
                    acc[i][j] = mfma_bf16(ahf[i], blf[j], acc[i][j]);
                    acc[i][j] = mfma_bf16(alf[i], bhf[j], acc[i][j]);
                }
        }
    }

    #pragma unroll
    for (int j = 0; j < 2; ++j) {
        int col = n0 + wave * 32 + 16 * j + fr;
        float bj = bias[col];
        #pragma unroll
        for (int i = 0; i < 4; ++i)
            #pragma unroll
            for (int r = 0; r < 4; ++r) {
                int row = m0 + 16 * i + g * 4 + r;
                Cout[(size_t)row * N + col] = acc[i][j][r] + bj;
            }
    }
}

// ---------------------------------------------------------------------------
// Flash attention v13 — in-block key-split, 8 waves (r15).
// r14 accounting: attn ~54 us at 2 waves/SIMD (grid 512 x 4 waves = 2
// blocks/CU); compute floor ~10 us, LDS floor ~15 us -> latency-bound.
// Now 512 threads: waves 0-3 scan keys [0,1024), waves 4-7 [1024,2048),
// same 128 q-rows. Each khalf group has its own 32 KB K/V LDS dbuf (64 KB
// total -> exactly 2 blocks/CU = 16 waves/CU = 4 waves/SIMD, double r14).
// Per-wave LDS bytes/tile unchanged -> LDS floor stays ~15 us. Linear
// combine (no running max) via LDS (stride-68 f32, 2-way alias = free)
// reusing the dead K/V buffers; zero extra global traffic (r13 lesson).
// PV re-phased by key-sub-block hh to halve live P-state and fit the
// (512,4) 128-VGPR cap (r9 spill mode watched: attn WRITE_SIZE must stay
// ~16 MB).
// ---------------------------------------------------------------------------
__global__ __launch_bounds__(512, 4)
void attn_mfma(const short* __restrict__ qkv, const short* __restrict__ kp,
               const short* __restrict__ vtp,
               short* __restrict__ ctxh, short* __restrict__ ctxl)
{
    // [khalf][dbuf][ K: 0..4095 | V: 4096..8191 ]  = 64 KB
    __shared__ __align__(16) short ldsKV[2][2][8192];

    const int tid  = threadIdx.x;
    const int lane = tid & 63;
    const int wave = tid >> 6;      // 0..7
    const int w4    = wave & 3;     // q-row group: rows [w4*32, +32)
    const int khalf = wave >> 2;    // key half
    const int fr = lane & 15;
    const int g  = lane >> 4;

    // 512 blocks = 8 XCD-groups x 4 bh x 16 q-blocks(128 rows)
    const int id = blockIdx.x;
    const int x = id & 7, y = id >> 3;
    const int bh = x * 4 + (y & 3);
    const int q0 = (y >> 2) * 128;
    const int b = bh >> 4, h = bh & 15;

    // ---- Q fragments: 2 sets of 16 rows (pre-scaled by QK_SCALE) ----
    short8 aq[2][2];
    #pragma unroll
    for (int set = 0; set < 2; ++set) {
        const short* qrow = qkv +
            ((size_t)(q0 + w4 * 32 + set * 16 + fr) * 2 + b) * 3072 + h * 192;
        aq[set][0] = *(const short8*)(qrow + g * 8);
        aq[set][1] = *(const short8*)(qrow + 32 + g * 8);
    }

    const short* kt = kp  + (size_t)bh * 131072 + (size_t)khalf * 16 * 4096;
    const short* vt = vtp + (size_t)bh * 131072 + (size_t)khalf * 16 * 4096;

    short8 ONES;
    #pragma unroll
    for (int i = 0; i < 8; ++i) ONES[i] = (short)0x3F80;  // bf16 1.0

    const f32x4 zero = {0.f, 0.f, 0.f, 0.f};
    f32x4 o[2][4];
    #pragma unroll
    for (int set = 0; set < 2; ++set)
        #pragma unroll
        for (int jd = 0; jd < 4; ++jd) o[set][jd] = zero;
    f32x4 lacc[2] = {zero, zero};

    // stage one 64-key tile (K 8KB + V 8KB) for this khalf into buffer sel
    auto stage = [&](int it, int sel) {
        const short* ks = kt + it * 4096 + w4 * 1024 + lane * 8;
        const short* vs = vt + it * 4096 + w4 * 1024 + lane * 8;
        short* base = &ldsKV[khalf][sel][0];
        gl2lds16(ks,       base + w4 * 1024);
        gl2lds16(ks + 512, base + w4 * 1024 + 512);
        gl2lds16(vs,       base + 4096 + w4 * 1024);
        gl2lds16(vs + 512, base + 4096 + w4 * 1024 + 512);
    };

    stage(0, 0);
    #pragma unroll 2
    for (int it = 0; it < 16; ++it) {
        const int cur = it & 1;
        __syncthreads();                 // stage(it) complete; buf cur^1 free
        if (it + 1 < 16) stage(it + 1, cur ^ 1);
        const short* Kb = &ldsKV[khalf][cur][0];
        const short* Vb = Kb + 4096;

        // ---- phase A: s = 0,1 -> A0; lacc; PV over even V frags ----
        union { int w[4]; short8 v; } A0[2];
        #pragma unroll
        for (int s = 0; s < 2; ++s) {
            short8 k0 = *(const short8*)&Kb[(2 * s) * 512 + lane * 8];
            short8 k1 = *(const short8*)&Kb[(2 * s + 1) * 512 + lane * 8];
            #pragma unroll
            for (int set = 0; set < 2; ++set) {
                f32x4 a = zero;
                a = mfma_bf16(k0, aq[set][0], a);
                a = mfma_bf16(k1, aq[set][1], a);
                float e0 = EXP2F(a[0]), e1 = EXP2F(a[1]);
                float e2 = EXP2F(a[2]), e3 = EXP2F(a[3]);
                A0[set].w[s * 2]     = pack_bf16(e1, e0);
                A0[set].w[s * 2 + 1] = pack_bf16(e3, e2);
            }
        }
        #pragma unroll
        for (int set = 0; set < 2; ++set)
            lacc[set] = mfma_bf16(A0[set].v, ONES, lacc[set]);
        #pragma unroll
        for (int jd = 0; jd < 4; ++jd) {
            short8 v0 = *(const short8*)&Vb[(2 * jd) * 512 + lane * 8];
            #pragma unroll
            for (int set = 0; set < 2; ++set)
                o[set][jd] = mfma_bf16(A0[set].v, v0, o[set][jd]);
        }

        // ---- phase B: s = 2,3 -> A1; lacc; PV over odd V frags ----
        union { int w[4]; short8 v; } A1[2];
        #pragma unroll
        for (int s = 0; s < 2; ++s) {
            short8 k0 = *(const short8*)&Kb[(2 * s + 4) * 512 + lane * 8];
            short8 k1 = *(const short8*)&Kb[(2 * s + 5) * 512 + lane * 8];
            #pragma unroll
            for (int set = 0; set < 2; ++set) {
                f32x4 a = zero;
                a = mfma_bf16(k0, aq[set][0], a);
                a = mfma_bf16(k1, aq[set][1], a);
                float e0 = EXP2F(a[0]), e1 = EXP2F(a[1]);
                float e2 = EXP2F(a[2]), e3 = EXP2F(a[3]);
                A1[set].w[s * 2]     = pack_bf16(e1, e0);
                A1[set].w[s * 2 + 1] = pack_bf16(e3, e2);
            }
        }
        #pragma unroll
        for (int set = 0; set < 2; ++set)
            lacc[set] = mfma_bf16(A1[set].v, ONES, lacc[set]);
        #pragma unroll
        for (int jd = 0; jd < 4; ++jd) {
            short8 v1 = *(const short8*)&Vb[(2 * jd + 1) * 512 + lane * 8];
            #pragma unroll
            for (int set = 0; set < 2; ++set)
                o[set][jd] = mfma_bf16(A1[set].v, v1, o[set][jd]);
        }
    }

    // ---- combine key halves via LDS (reuse dead K/V buffers) ----
    __syncthreads();                     // all LDS reads of the loop done
    float* oshare = (float*)&ldsKV[0][0][0];   // [128][68] f32 (34.8 KB)
    float* lshare = oshare + 128 * 68;         // [128]

    if (khalf == 1) {
        #pragma unroll
        for (int set = 0; set < 2; ++set)
            #pragma unroll
            for (int r = 0; r < 4; ++r) {
                int row = w4 * 32 + set * 16 + 4 * g + r;
                #pragma unroll
                for (int jd = 0; jd < 4; ++jd)
                    oshare[row * 68 + 16 * jd + fr] = o[set][jd][r];
                if (fr == 0) lshare[row] = lacc[set][r];
            }
    }
    __syncthreads();
    if (khalf == 0) {
        #pragma unroll
        for (int set = 0; set < 2; ++set)
            #pragma unroll
            for (int r = 0; r < 4; ++r) {
                int row = w4 * 32 + set * 16 + 4 * g + r;
                float lt = lacc[set][r] + lshare[row];
                float inv = 1.f / lt;
                int t = q0 + row;
                size_t base = ((size_t)t * B_DIM + b) * E_DIM + h * 64;
                #pragma unroll
                for (int jd = 0; jd < 4; ++jd) {
                    float v = (o[set][jd][r] + oshare[row * 68 + 16 * jd + fr]) * inv;
                    short hs = f2bf(v);
                    short ls = f2bf(v - bf2f(hs));
                    ctxh[base + 16 * jd + fr] = hs;
                    ctxl[base + 16 * jd + fr] = ls;
                }
            }
    }
}

// ---------------------------------------------------------------------------
extern "C" void kernel_launch(void* const* d_in, const int* in_sizes, int n_in,
                              void* d_out, int out_size, void* d_ws, size_t ws_size,
                              hipStream_t stream)
{
    const float* query = (const float*)d_in[0];
    const float* w_in  = (const float*)d_in[1];
    const float* b_in  = (const float*)d_in[2];
    const float* w_out = (const float*)d_in[3];
    const float* b_out = (const float*)d_in[4];
    float* out = (float*)d_out;

    char* ws = (char*)d_ws;
    short* qkv  = (short*)(ws);                  // 25.2 MB (Q cols live)
    short* qh   = (short*)(ws + 25165824);       // 8.4 MB
    short* wih  = (short*)(ws + 33554432);       // 6.3 MB
    short* wil  = (short*)(ws + 39845888);       // 6.3 MB
    short* woh  = (short*)(ws + 46137344);       // 2.1 MB
    short* wol  = (short*)(ws + 48234496);       // 2.1 MB
    short* vtp  = (short*)(ws + 50331648);       // 8.4 MB  V frag-order
    short* kp   = (short*)(ws + 58720256);       // 8.4 MB  K frag-order
    short* ctxh = (short*)(ws + 25165824);       // alias qh  (dead after in_proj)
    short* ctxl = (short*)(ws + 33554432);       // alias wih (dead after in_proj)

    const int M = T_DIM * B_DIM;  // 4096

    int nq4  = (M * E_DIM) / 4;
    int nwi4 = (3 * E_DIM * E_DIM) / 4;
    int nwo4 = (E_DIM * E_DIM) / 4;
    split_all_kernel<<<(nq4 + nwi4 + nwo4) / 256, 256, 0, stream>>>(
        query, w_in, w_out, qh, wih, wil, woh, wol, nq4, nwi4, nwo4);

    // in_proj + fused repack: Q -> qkv (scaled), K -> kp, V -> vtp
    gemm_in<<<dim3(3 * E_DIM / 128, M / 128), 256, 0, stream>>>(
        qh, wih, wil, b_in, qkv, kp, vtp, M, 3 * E_DIM, E_DIM);

    // attention: 512 blocks x 512 threads (8 waves: 4 q-groups x 2 key-halves)
    attn_mfma<<<dim3(512), 512, 0, stream>>>(qkv, kp, vtp, ctxh, ctxl);

    // out_proj: 64x128 tiles -> 512 blocks, full split, 3 MFMA, BK=64
    gemm_out<<<dim3(E_DIM / 128, M / 64), 256, 0, stream>>>(
        ctxh, ctxl, woh, wol, b_out, out, M, E_DIM, E_DIM);
}